// Round 4
// baseline (3213.689 us; speedup 1.0000x reference)
//
#include <hip/hip_runtime.h>
#include <hip/hip_bf16.h>

// B=32, T=128, I=H=O=512, L=2 bidir GRU + FC, cross-layer wavefront pipeline.
// ws layout:
//   proj0 (bf16): [2d][128][32][1536] = 12,582,912 e * 2B = 25,165,824 B
//   seq0  (fp32): [2d][128][32][512]  =  4,194,304 f
//   rslabs(fp32): [4ld][128jb][6144]  =  3,145,728 f   (recur weights, both layers)
//   islabs(fp32): [2d][128cb][6144]   =  1,572,864 f   (layer-1 input-proj weights)
//   p1    (fp32): [2slot][2d][32][1536] = 196,608 f    (layer-1 proj ring)
//   h1ring(fp32): [2slot][2d][32][512]  =  65,536 f
//   fcin  (fp32): [2][32][512]          =  32,768 f
// total ~62.0 MB

// ---------------- proj GEMM (layer 0 only): [8192 x 1536] -> bf16 ----------------
__global__ __launch_bounds__(256)
void proj_kernel(const float* __restrict__ src,
                 const float* __restrict__ Wxh, const float* __restrict__ bxh,
                 const float* __restrict__ Wxr, const float* __restrict__ bxr,
                 __hip_bfloat16* __restrict__ proj)
{
    __shared__ float As[32][137];
    __shared__ float Ws[32][132];
    const int tid  = threadIdx.x;
    const int col0 = blockIdx.x * 128;
    const int row0 = blockIdx.y * 128;
    const int d    = row0 >> 12;
    const int ld   = d;                      // layer 0
    const int tx = tid & 15, ty = tid >> 4;

    const bool is_xr = (col0 >= 1024);
    const float* Wbase = is_xr ? (Wxr + (size_t)ld * 512 * 512 + (col0 - 1024))
                               : (Wxh + (size_t)ld * 512 * 1024 + col0);
    const int wstride = is_xr ? 512 : 1024;
    const float* bias = is_xr ? (bxr + ld * 512 + (col0 - 1024))
                              : (bxh + ld * 1024 + col0);

    float acc[8][8];
    #pragma unroll
    for (int i = 0; i < 8; i++)
        #pragma unroll
        for (int j = 0; j < 8; j++) acc[i][j] = 0.f;

    for (int k0 = 0; k0 < 512; k0 += 32) {
        #pragma unroll
        for (int v = 0; v < 4; v++) {
            int idx = tid + v * 256;
            int r   = idx >> 3;
            int c4  = (idx & 7) << 2;
            int gm  = row0 + r;
            int rr  = gm & 4095;
            int tt  = rr >> 5, bb = rr & 31;
            int ts  = (gm >= 4096) ? (127 - tt) : tt;   // dir1 reads reversed time
            const float* p = src + ((size_t)bb * 128 + ts) * 512 + (k0 + c4);
            float4 vv = *(const float4*)p;
            As[c4 + 0][r] = vv.x; As[c4 + 1][r] = vv.y;
            As[c4 + 2][r] = vv.z; As[c4 + 3][r] = vv.w;
        }
        #pragma unroll
        for (int v = 0; v < 4; v++) {
            int idx = tid + v * 256;
            int kr  = idx >> 5;
            int c4  = (idx & 31) << 2;
            *(float4*)&Ws[kr][c4] = *(const float4*)(Wbase + (size_t)(k0 + kr) * wstride + c4);
        }
        __syncthreads();
        #pragma unroll
        for (int kk = 0; kk < 32; kk++) {
            float a[8], w[8];
            *(float4*)&a[0] = *(const float4*)&As[kk][ty * 8];
            *(float4*)&a[4] = *(const float4*)&As[kk][ty * 8 + 4];
            *(float4*)&w[0] = *(const float4*)&Ws[kk][tx * 8];
            *(float4*)&w[4] = *(const float4*)&Ws[kk][tx * 8 + 4];
            #pragma unroll
            for (int i = 0; i < 8; i++)
                #pragma unroll
                for (int j = 0; j < 8; j++)
                    acc[i][j] += a[i] * w[j];
        }
        __syncthreads();
    }
    #pragma unroll
    for (int i = 0; i < 8; i++) {
        int gm = row0 + ty * 8 + i;
        __hip_bfloat16* dst = proj + (size_t)gm * 1536 + col0 + tx * 8;
        #pragma unroll
        for (int j = 0; j < 8; j++)
            dst[j] = __float2bfloat16(acc[i][j] + bias[tx * 8 + j]);
    }
}

// ---------------- recur weight repack (both layers): slab[(ld*128+jb)] ----------------
__global__ __launch_bounds__(256)
void repack_kernel(const float* __restrict__ Whh, const float* __restrict__ Whr,
                   float* __restrict__ slabs)
{
    const int blk = blockIdx.x;           // 0..511 = ld*128 + jb
    const int ld = blk >> 7, jb = blk & 127;
    const float* WhhL = Whh + (size_t)ld * 512 * 1024;
    const float* WhrL = Whr + (size_t)ld * 512 * 512;
    float* out = slabs + (size_t)blk * 6144;
    for (int u = 0; u < 24; u++) {
        int idx = threadIdx.x + u * 256;
        int rec = idx / 12, r3 = idx % 12;
        int g = rec >> 2, cg = rec & 3;
        int e = r3 >> 2, ki = r3 & 3;
        int k = g * 4 + ki, j = jb * 4 + cg;
        float v;
        if (e == 0)      v = WhhL[(size_t)k * 1024 + j];
        else if (e == 1) v = WhhL[(size_t)k * 1024 + 512 + j];
        else             v = WhrL[(size_t)k * 512 + j];
        out[idx] = v;
    }
}

// ---------------- layer-1 input-proj weight repack: islabs[(d*128+cb)] ----------------
// record (g,cg): 3 consecutive cols {cb*12+cg*3+e} as float4 over k-quad g.
__global__ __launch_bounds__(256)
void irepack_kernel(const float* __restrict__ Wxh, const float* __restrict__ Wxr,
                    float* __restrict__ islabs)
{
    const int blk = blockIdx.x;           // 0..255 = d*128 + cb
    const int d = blk >> 7, cb = blk & 127;
    const float* WxhL = Wxh + (size_t)(2 + d) * 512 * 1024;
    const float* WxrL = Wxr + (size_t)(2 + d) * 512 * 512;
    float* out = islabs + (size_t)blk * 6144;
    for (int u = 0; u < 24; u++) {
        int idx = threadIdx.x + u * 256;
        int rec = idx / 12, r3 = idx % 12;
        int g = rec >> 2, cg = rec & 3;
        int e = r3 >> 2, ki = r3 & 3;
        int k = g * 4 + ki, c = cb * 12 + cg * 3 + e;
        out[idx] = (c < 1024) ? WxhL[(size_t)k * 1024 + c]
                              : WxrL[(size_t)k * 512 + (c - 1024)];
    }
}

// ---------------- shared recur body ----------------
template<bool BF16P>
__device__ __forceinline__ void recur_body(float* hs, int tid, int jb, int ld,
    const float* hsrc, const float4* wrec, const void* projrow,
    const float* __restrict__ bhh, const float* __restrict__ bhr,
    float* out_h, float* out_fc)
{
    const int cg = tid & 3, kh = (tid >> 2) & 1, b = tid >> 3, sb = b & 7;
    const int j = jb * 4 + cg;
    float az = 0.f, ar = 0.f, ag = 0.f, hv_self = 0.f;
    if (hsrc) {
        #pragma unroll
        for (int v = 0; v < 16; v++) {
            int id = tid + v * 256;
            int bb = id >> 7, g = id & 127;
            float4 hv = *(const float4*)(hsrc + (size_t)id * 4);
            *(float4*)&hs[bb * 512 + ((g ^ (bb & 7)) << 2)] = hv;
        }
        __syncthreads();
        #pragma unroll 4
        for (int gg = 0; gg < 64; gg++) {
            int g = kh * 64 + gg;
            float4 h4 = *(const float4*)&hs[b * 512 + ((g ^ sb) << 2)];
            const float4* wp = wrec + (size_t)(g * 4 + cg) * 3;
            float4 wz = wp[0], wr = wp[1], wg = wp[2];
            az += h4.x*wz.x + h4.y*wz.y + h4.z*wz.z + h4.w*wz.w;
            ar += h4.x*wr.x + h4.y*wr.y + h4.z*wr.z + h4.w*wr.w;
            ag += h4.x*wg.x + h4.y*wg.y + h4.z*wg.z + h4.w*wg.w;
        }
        az += __shfl_xor(az, 4, 64);
        ar += __shfl_xor(ar, 4, 64);
        ag += __shfl_xor(ag, 4, 64);
        hv_self = hs[b * 512 + ((jb ^ sb) << 2) + cg];
    }
    float pz, pr, pg;
    if (BF16P) {
        const __hip_bfloat16* pp = (const __hip_bfloat16*)projrow + (size_t)b * 1536;
        pz = __bfloat162float(pp[j]);
        pr = __bfloat162float(pp[512 + j]);
        pg = __bfloat162float(pp[1024 + j]);
    } else {
        const float* pp = (const float*)projrow + (size_t)b * 1536;
        pz = pp[j]; pr = pp[512 + j]; pg = pp[1024 + j];
    }
    float z  = 1.f / (1.f + __expf(-(az + pz + bhh[ld * 1024 + j])));
    float r  = 1.f / (1.f + __expf(-(ar + pr + bhh[ld * 1024 + 512 + j])));
    float gt = tanhf((ag + bhr[ld * 512 + j]) * r + pg);
    float hn = z * hv_self + (1.f - z) * gt;
    if (kh == 0) {
        out_h[(size_t)b * 512 + j] = hn;
        if (out_fc) out_fc[(size_t)b * 512 + j] = hn;
    }
}

// ---------------- pipeline tick: L0-recur(t=L) | L1-inproj(t=L-1) | L1-recur(t=L-2) ----------------
__global__ __launch_bounds__(256)
void pipe_kernel(const __hip_bfloat16* __restrict__ proj0, float* __restrict__ seq0,
                 const float* __restrict__ rslabs, const float* __restrict__ islabs,
                 float* __restrict__ p1, float* __restrict__ h1ring,
                 float* __restrict__ fcin,
                 const float* __restrict__ bhh, const float* __restrict__ bhr,
                 const float* __restrict__ bxh, const float* __restrict__ bxr, int L)
{
    __shared__ __align__(16) float hs[32 * 512];
    const int blk = blockIdx.x, tid = threadIdx.x;

    if (blk < 256) {                       // ---- layer 0 recurrence, t = L ----
        if (L > 127) return;
        const int d = blk >> 7, jb = blk & 127, t = L;
        const float* hsrc = (t == 0) ? nullptr
                          : seq0 + (size_t)(d * 128 + (t - 1)) * 32 * 512;
        const float4* wrec = (const float4*)rslabs + (size_t)(d * 128 + jb) * 1536;
        const void* projrow = proj0 + (size_t)(d * 128 + t) * 32 * 1536;
        recur_body<true>(hs, tid, jb, d, hsrc, wrec, projrow, bhh, bhr,
                         seq0 + (size_t)(d * 128 + t) * 32 * 512, nullptr);
    } else if (blk < 512) {                // ---- layer 1 recurrence, t = L-2 ----
        if (L < 2) return;
        const int t1 = L - 2;
        const int d = (blk - 256) >> 7, jb = blk & 127;
        const float* hsrc = (t1 == 0) ? nullptr
                          : h1ring + (size_t)((((t1 - 1) & 1) * 2) + d) * 32 * 512;
        const float4* wrec = (const float4*)rslabs + (size_t)((2 + d) * 128 + jb) * 1536;
        const void* projrow = p1 + (size_t)(((t1 & 1) * 2) + d) * 32 * 1536;
        float* out_fc = nullptr;
        if (d == 0 && t1 == 127) out_fc = fcin;                 // seq_f[-1]
        if (d == 1 && t1 == 0)   out_fc = fcin + 32 * 512;      // seq_r[0]
        recur_body<false>(hs, tid, jb, 2 + d, hsrc, wrec, projrow, bhh, bhr,
                          h1ring + (size_t)(((t1 & 1) * 2) + d) * 32 * 512, out_fc);
    } else {                               // ---- layer 1 input proj, t = L-1 ----
        if (L < 1 || L > 128) return;
        const int tp = L - 1;
        const int d = (blk - 512) >> 7, cb = blk & 127;
        const int cg = tid & 3, kh = (tid >> 2) & 1, b = tid >> 3, sb = b & 7;
        const float* xsrc = seq0 + (size_t)(d * 128 + tp) * 32 * 512;
        #pragma unroll
        for (int v = 0; v < 16; v++) {
            int id = tid + v * 256;
            int bb = id >> 7, g = id & 127;
            float4 hv = *(const float4*)(xsrc + (size_t)id * 4);
            *(float4*)&hs[bb * 512 + ((g ^ (bb & 7)) << 2)] = hv;
        }
        __syncthreads();
        const float4* wrec = (const float4*)islabs + (size_t)(d * 128 + cb) * 1536;
        float a0 = 0.f, a1 = 0.f, a2 = 0.f;
        #pragma unroll 4
        for (int gg = 0; gg < 64; gg++) {
            int g = kh * 64 + gg;
            float4 h4 = *(const float4*)&hs[b * 512 + ((g ^ sb) << 2)];
            const float4* wp = wrec + (size_t)(g * 4 + cg) * 3;
            float4 w0 = wp[0], w1 = wp[1], w2 = wp[2];
            a0 += h4.x*w0.x + h4.y*w0.y + h4.z*w0.z + h4.w*w0.w;
            a1 += h4.x*w1.x + h4.y*w1.y + h4.z*w1.z + h4.w*w1.w;
            a2 += h4.x*w2.x + h4.y*w2.y + h4.z*w2.z + h4.w*w2.w;
        }
        a0 += __shfl_xor(a0, 4, 64);
        a1 += __shfl_xor(a1, 4, 64);
        a2 += __shfl_xor(a2, 4, 64);
        if (kh == 0) {
            const int c0 = cb * 12 + cg * 3;
            float* dst = p1 + (size_t)(((tp & 1) * 2) + d) * 32 * 1536
                            + (size_t)b * 1536 + c0;
            float acc[3] = {a0, a1, a2};
            #pragma unroll
            for (int e = 0; e < 3; e++) {
                int c = c0 + e;
                float bias = (c < 1024) ? bxh[(size_t)(2 + d) * 1024 + c]
                                        : bxr[(size_t)(2 + d) * 512 + (c - 1024)];
                dst[e] = acc[e] + bias;
            }
        }
    }
}

// ---------------- final FC ----------------
__global__ __launch_bounds__(256)
void fc_kernel(const float* __restrict__ fcin, const float* __restrict__ Wfc,
               const float* __restrict__ bfc, float* __restrict__ out)
{
    int idx = blockIdx.x * 256 + threadIdx.x;   // 0..16383
    int b = idx >> 9, o = idx & 511;
    const float* catf = fcin + (size_t)b * 512;
    const float* catr = fcin + 32 * 512 + (size_t)b * 512;
    float acc = bfc[o];
    #pragma unroll 8
    for (int k = 0; k < 512; k++) acc += catf[k] * Wfc[(size_t)k * 512 + o];
    #pragma unroll 8
    for (int k = 0; k < 512; k++) acc += catr[k] * Wfc[(size_t)(512 + k) * 512 + o];
    out[(size_t)b * 512 + o] = acc;
}

extern "C" void kernel_launch(void* const* d_in, const int* in_sizes, int n_in,
                              void* d_out, int out_size, void* d_ws, size_t ws_size,
                              hipStream_t stream) {
    (void)in_sizes; (void)n_in; (void)out_size; (void)ws_size;
    const float* x   = (const float*)d_in[0];
    const float* Wxh = (const float*)d_in[1];
    const float* bxh = (const float*)d_in[2];
    const float* Whh = (const float*)d_in[3];
    const float* bhh = (const float*)d_in[4];
    const float* Wxr = (const float*)d_in[5];
    const float* bxr = (const float*)d_in[6];
    const float* Whr = (const float*)d_in[7];
    const float* bhr = (const float*)d_in[8];
    const float* Wfc = (const float*)d_in[9];
    const float* bfc = (const float*)d_in[10];
    float* out = (float*)d_out;

    char* base = (char*)d_ws;
    __hip_bfloat16* proj0 = (__hip_bfloat16*)base;
    float* seq0   = (float*)(base + 25165824);
    float* rslabs = seq0   + 4194304;
    float* islabs = rslabs + 3145728;
    float* p1     = islabs + 1572864;
    float* h1ring = p1     + 196608;
    float* fcin   = h1ring + 65536;

    repack_kernel<<<512, 256, 0, stream>>>(Whh, Whr, rslabs);
    irepack_kernel<<<256, 256, 0, stream>>>(Wxh, Wxr, islabs);

    dim3 pgrid(12, 64);
    proj_kernel<<<pgrid, 256, 0, stream>>>(x, Wxh, bxh, Wxr, bxr, proj0);

    for (int L = 0; L < 130; L++)
        pipe_kernel<<<768, 256, 0, stream>>>(proj0, seq0, rslabs, islabs, p1,
                                             h1ring, fcin, bhh, bhr, bxh, bxr, L);

    fc_kernel<<<64, 256, 0, stream>>>(fcin, Wfc, bfc, out);
}